// Round 19
// baseline (87.794 us; speedup 1.0000x reference)
//
#include <hip/hip_runtime.h>
#include <hip/hip_bf16.h>
#include <math.h>

#define B_ 8
#define C_ 256
#define N_ 1024
#define H_ 8
#define DH 96
#define BHN (C_*3*N_)
#define SC 0.10206207261596575f     // 1/sqrt(96)
#define SCL2 0.14722193f            // SC * log2(e): QK scores in log2 domain

typedef _Float16 half8 __attribute__((ext_vector_type(8)));
typedef float f32x4 __attribute__((ext_vector_type(4)));
typedef float f32x16 __attribute__((ext_vector_type(16)));

typedef __attribute__((address_space(1))) void gvoid;
typedef __attribute__((address_space(3))) void lvoid;
__device__ inline void gl_lds16(const _Float16* g, _Float16* l) {
  __builtin_amdgcn_global_load_lds((gvoid*)g, (lvoid*)l, 16, 0, 0);
}

__device__ inline float ex2(float x) { return __builtin_amdgcn_exp2f(x); }

typedef __fp16 fp16x2 __attribute__((ext_vector_type(2)));
union H2U { fp16x2 h2; unsigned u; };
__device__ inline unsigned pkh(float a, float b) {
  H2U x; x.h2 = __builtin_amdgcn_cvt_pkrtz(a, b); return x.u;
}
union PF { half8 v; unsigned u[4]; };

// v_permlane32_swap_b32: a' = [a_lo|b_lo], b' = [a_hi|b_hi]
__device__ inline void plswap(unsigned& a, unsigned& b) {
  asm volatile("v_permlane32_swap_b32 %0, %1" : "+v"(a), "+v"(b));
}

// ---------------------------------------------------------------------------
// Fused prep kernel. z<8: transpose-convert x -> XT fp16 n-major.
// z==8 bid<128: W fp32->fp16. bid==128: KEY COMPACTION — stable partition of
// tokens per batch (unmasked -> slots [0,cnt)); emits INVERSE permutation
// invpos[b][slot]=token (gather side), nt[b]=ceil(cnt/64), and per-(b,t)
// bitmask (0 for full tiles, ~0<<rem for the last partial tile).
// ---------------------------------------------------------------------------
__global__ __launch_bounds__(256) void prep_kernel(
    const float* __restrict__ x, _Float16* __restrict__ XT,
    const float* __restrict__ Wq, const float* __restrict__ Wk,
    const float* __restrict__ Wv, const float* __restrict__ Wp,
    _Float16* __restrict__ Wh, const unsigned* __restrict__ mraw,
    unsigned long long* __restrict__ mb, int* __restrict__ invpos,
    int* __restrict__ ntArr) {
  if (blockIdx.z == 8) {
    int bid = blockIdx.y * 48 + blockIdx.x;
    const int tid = threadIdx.x;
    if (bid < 128) {
      int idx = bid * 256 + tid;
      int e0 = idx * 8;
      const float* src = (e0 < 65536) ? Wq
                       : (e0 < 131072) ? Wk
                       : (e0 < 196608) ? Wv : Wp;
      int off = e0 & 65535;
      float4 a = *(const float4*)&src[off];
      float4 b = *(const float4*)&src[off + 4];
      _Float16 t[8] = {(_Float16)a.x, (_Float16)a.y, (_Float16)a.z,
                       (_Float16)a.w, (_Float16)b.x, (_Float16)b.y,
                       (_Float16)b.z, (_Float16)b.w};
      *(uint4*)&Wh[e0] = *(uint4*)t;
    } else if (bid == 128) {
      __shared__ int notI, notF;
      __shared__ int cnts[256];
      if (tid == 0) { notI = 0; notF = 0; }
      __syncthreads();
      int li = 0, lf = 0;
      for (int i = tid; i < 2048; i += 256) {
        unsigned w = mraw[i];
        if (w > 1u) li = 1;
        if (w != 0u && w != 0x3F800000u) lf = 1;
      }
      if (li) atomicOr(&notI, 1);
      if (lf) atomicOr(&notF, 1);
      __syncthreads();
      const int nI = notI, nF = notF;
      auto ispad = [&](int idx) -> int {
        if (!nI) return (int)(mraw[idx] & 1u);
        if (!nF) return (mraw[idx] != 0u) ? 1 : 0;
        return ((const unsigned char*)mraw)[idx] ? 1 : 0;
      };
      const int gb = tid >> 5, gi = tid & 31;   // batch, 32 threads each
      const int tbase = gb * 1024 + gi * 32;    // 32 tokens per thread
      int cloc = 0;
      for (int j = 0; j < 32; ++j) cloc += 1 - ispad(tbase + j);
      cnts[tid] = cloc;
      __syncthreads();
      int pre = 0, tot = 0;
      for (int k2 = 0; k2 < 32; ++k2) {
        int v = cnts[gb * 32 + k2];
        if (k2 < gi) pre += v;
        tot += v;
      }
      int pu = pre;                       // next unmasked compact slot
      int pm = tot + (gi * 32 - pre);     // next masked compact slot
      for (int j = 0; j < 32; ++j) {
        int tok = gi * 32 + j;
        int pd = ispad(tbase + j);
        int p = pd ? pm++ : pu++;
        invpos[gb * 1024 + p] = tok;      // inverse: slot -> token
      }
      if (gi == 0) {
        int nt = (tot + 63) >> 6;
        if (nt == 0) nt = 1;
        ntArr[gb] = nt;
        int rem = tot & 63;
        for (int t = 0; t < 16; ++t) {
          unsigned long long bits;
          if (t < nt - 1) bits = 0ULL;
          else if (t == nt - 1)
            bits = (rem == 0 && tot > 0) ? 0ULL : (~0ULL << rem);
          else bits = ~0ULL;
          mb[gb * 16 + t] = bits;
        }
      }
    }
    return;
  }

  __shared__ _Float16 T[64][65];
  const int m0 = blockIdx.x * 64;
  const int c0 = blockIdx.y * 64;
  const int b = blockIdx.z;
  const float* xb = x + (size_t)b * BHN;
  _Float16* ob = XT + (size_t)b * BHN;
  const int t = threadIdx.x;
#pragma unroll
  for (int i = 0; i < 16; ++i) {
    int e = t + i * 256;
    int c = e >> 6, m = e & 63;
    T[m][c] = (_Float16)xb[(size_t)(c0 + c) * 3072 + m0 + m];
  }
  __syncthreads();
#pragma unroll
  for (int i = 0; i < 2; ++i) {
    int e = t + i * 256;
    int m = e >> 3, ch = e & 7;
    _Float16 tmp[8];
#pragma unroll
    for (int j = 0; j < 8; ++j) tmp[j] = T[m][ch * 8 + j];
    *(uint4*)&ob[(size_t)(m0 + m) * 256 + c0 + ch * 8] = *(uint4*)tmp;
  }
}

// ---------------------------------------------------------------------------
// fp16 MFMA GEMM: O = W(256x256) @ X[b](256x3072), X n-major [n][c].
// 256(o) x 128(n) block tile (single o-tile: B staged ONCE per n-tile),
// BK=64, both-sides XOR chunk swizzle (rule #21). 4 waves as 2x2, wave tile
// 128(o) x 64(n), acc[8][4]. __launch_bounds__(256,2): 2 blocks/CU,
// 48KB LDS, ~200 VGPR < 256 cap.
// MODE 0: k/v (w=1,2) GATHER B rows through invpos; skip n-tiles fully
// beyond nt[b]*64 compact slots. Outputs packed for attention:
//   w=0 Qp[bh][qt32][ks6][ql32][hi2][8]  (scaled by SCL2)
//   w=1 Kp[bh][t16][ks6][kk64][hi2][8]   (kk = compact slot)
//   w=2 Vp[bh][t16][kt4][dt3][lq32][hi2][8]
// MODE 1: Of c-major fp32 (final out).
// ---------------------------------------------------------------------------
template <int MODE>
__global__ __launch_bounds__(256, 2) void mgemm_kernel(
    const _Float16* __restrict__ Wh, int woff,
    const _Float16* __restrict__ Xn, const int* __restrict__ invpos,
    const int* __restrict__ ntArr,
    _Float16* __restrict__ O0, _Float16* __restrict__ O1,
    _Float16* __restrict__ O2, float* __restrict__ Of, int nw) {
  const int zz = blockIdx.z;
  const int w = zz % nw;
  const int b = zz / nw;
  const int bn0 = blockIdx.x * 128;

  if constexpr (MODE == 0) {
    // k/v: skip n-tiles fully beyond the compact-slot range used by attn
    if (w != 0 && (bn0 & 1023) >= ntArr[b] * 64) return;
  }

  const _Float16* Wb = Wh + (size_t)(woff + w) * 65536;
  const _Float16* Bb = Xn + (size_t)b * BHN;

  __shared__ __align__(16) _Float16 Ah[16384];  // [256][64], chunk-swizzled
  __shared__ __align__(16) _Float16 Bh[8192];   // [128][64], chunk-swizzled

  const int tid = threadIdx.x;
  const int wave = tid >> 6;
  const int lane = tid & 63;
  const int lg = lane >> 4, ll = lane & 15;
  const int wm = wave >> 1, wn = wave & 1;

  // per-thread B-tile source rows (fixed across k0); k/v gather via invpos
  int srows[4];
#pragma unroll
  for (int i = 0; i < 4; ++i) {
    int e = tid + i * 256;
    int r = e >> 3;
    int mrow = bn0 + r;
    if constexpr (MODE == 0) {
      if (w != 0) {
        int dd = mrow >> 10, tk = mrow & 1023;
        mrow = dd * 1024 + invpos[b * 1024 + tk];
      }
    }
    srows[i] = mrow;
  }

  f32x4 acc[8][4];
#pragma unroll
  for (int mi = 0; mi < 8; ++mi)
#pragma unroll
    for (int ni = 0; ni < 4; ++ni) acc[mi][ni] = (f32x4){0.f, 0.f, 0.f, 0.f};

  for (int k0 = 0; k0 < 256; k0 += 64) {
    // A: 256 rows x 8 chunks = 2048 chunks, 8 per thread
#pragma unroll
    for (int i = 0; i < 8; ++i) {
      int e = tid + i * 256;
      int r = e >> 3, cch = e & 7;
      int srcc = cch ^ (r & 7);
      gl_lds16(Wb + (size_t)r * 256 + k0 + srcc * 8,
               &Ah[(size_t)(i * 256 + wave * 64) * 8]);
    }
    // B: 128 rows x 8 chunks = 1024 chunks, 4 per thread (gathered rows)
#pragma unroll
    for (int i = 0; i < 4; ++i) {
      int e = tid + i * 256;
      int r = e >> 3, cch = e & 7;
      int srcc = cch ^ (r & 7);
      gl_lds16(Bb + (size_t)srows[i] * 256 + k0 + srcc * 8,
               &Bh[(size_t)(i * 256 + wave * 64) * 8]);
    }
    __syncthreads();
#pragma unroll
    for (int kk = 0; kk < 2; ++kk) {
      half8 af[8], bf[4];
#pragma unroll
      for (int mi = 0; mi < 8; ++mi) {
        int row = wm * 128 + mi * 16 + ll;
        int ch = (kk * 4 + lg) ^ (row & 7);
        af[mi] = *(const half8*)&Ah[row * 64 + ch * 8];
      }
#pragma unroll
      for (int ni = 0; ni < 4; ++ni) {
        int row = wn * 64 + ni * 16 + ll;
        int ch = (kk * 4 + lg) ^ (row & 7);
        bf[ni] = *(const half8*)&Bh[row * 64 + ch * 8];
      }
#pragma unroll
      for (int mi = 0; mi < 8; ++mi)
#pragma unroll
        for (int ni = 0; ni < 4; ++ni)
          acc[mi][ni] = __builtin_amdgcn_mfma_f32_16x16x32_f16(
              af[mi], bf[ni], acc[mi][ni], 0, 0, 0);
    }
    __syncthreads();
  }

#pragma unroll
  for (int mi = 0; mi < 8; ++mi) {
#pragma unroll
    for (int ni = 0; ni < 4; ++ni) {
      int o = wm * 128 + mi * 16 + lg * 4;       // channel (4 consecutive via r)
      int mcol = bn0 + wn * 64 + ni * 16 + ll;   // dd*1024 + token/slot
      if constexpr (MODE == 1) {
        float* Ofb = Of + (size_t)b * BHN;
#pragma unroll
        for (int r = 0; r < 4; ++r)
          Ofb[(size_t)(o + r) * 3072 + mcol] = acc[mi][ni][r];
      } else {
        const int h = o >> 5, i = o & 31;
        const int dd = mcol >> 10, tok = mcol & 1023;
        const size_t bh8 = (size_t)(b * 8 + h);
        if (w == 2) {
          // Vp[bh][t][kt][dt=dd][lq=i(+r)][hi2][e]  (tok = compact slot)
          int tt = tok >> 6, kk = tok & 63;
          int kt = kk >> 4, hi2 = (kk >> 3) & 1, e = kk & 7;
          size_t base = ((((bh8 * 16 + tt) * 4 + kt) * 3 + dd) * 512) +
                        (size_t)i * 16 + hi2 * 8 + e;
#pragma unroll
          for (int r = 0; r < 4; ++r)
            O2[base + r * 16] = (_Float16)acc[mi][ni][r];
        } else {
          int dperm = dd * 32 + i;
          int pp = dperm >> 3, j0 = i & 7;
          int ks = pp >> 1, hif = pp & 1;
          float qs = (w == 0) ? SCL2 : 1.0f;
          _Float16 t4[4];
#pragma unroll
          for (int r = 0; r < 4; ++r) t4[r] = (_Float16)(acc[mi][ni][r] * qs);
          size_t idx;
          if (w == 0) {
            // Qp[bh][qt32][ks][ql][hi][j]
            idx = ((bh8 * 32 + (tok >> 5)) * 6 + ks) * 512 +
                  (size_t)(tok & 31) * 16 + hif * 8 + j0;
            *(uint2*)&O0[idx] = *(uint2*)t4;
          } else {
            // Kp[bh][t][ks][kk][hi][j]  (tok = compact slot)
            idx = ((bh8 * 16 + (tok >> 6)) * 6 + ks) * 1024 +
                  (size_t)(tok & 63) * 16 + hif * 8 + j0;
            *(uint2*)&O1[idx] = *(uint2*)t4;
          }
        }
      }
    }
  }
}

// ---------------------------------------------------------------------------
// Flash attention — r9 structure + key compaction (loop over nt[b] tiles).
// 32x32 swapped-QK^T, LDS-free, barrier-free, packed fragment-major q/k/v.
// Softmax exp2 domain, defer-max THR=12, permlane P-repack.
// C/D map: col=lane&31, row=(r&3)+8*(r>>2)+4*(lane>>5).
// ---------------------------------------------------------------------------
__global__ __launch_bounds__(256, 2) void attn_kernel(
    const _Float16* __restrict__ Qp, const _Float16* __restrict__ Kp,
    const _Float16* __restrict__ Vp,
    const unsigned long long* __restrict__ mbits,
    const int* __restrict__ ntArr, _Float16* __restrict__ yT) {
  const int gid = blockIdx.x;
  const int bh = gid & 63;   // XCD = gid%8 = h: per-XCD K/V set L2-resident
  const int qt = gid >> 6;
  const int b = bh >> 3, h = bh & 7;
  const int n0 = qt * 128;
  const int nt = ntArr[b];

  const int tid = threadIdx.x;
  const int lane = tid & 63;
  const int wave = tid >> 6;
  const int hi = lane >> 5;
  const int lq = lane & 31;
  const int wq0 = wave * 32;

  const size_t bh8 = (size_t)(b * 8 + h);
  const int lo16 = lq * 16 + hi * 8;

  const _Float16* Qb = Qp + (bh8 * 32 + (qt * 4 + wave)) * 6 * 512 + lo16;
  half8 qf[6];
#pragma unroll
  for (int ks = 0; ks < 6; ++ks) qf[ks] = *(const half8*)(Qb + ks * 512);

  const _Float16* Kh = Kp + bh8 * 98304 + lo16;
  const _Float16* Vh = Vp + bh8 * 98304 + lo16;

  half8 kf[6][2];
  auto loadK = [&](int t) {
    const _Float16* Kt = Kh + t * 6144;
#pragma unroll
    for (int ks = 0; ks < 6; ++ks) {
      kf[ks][0] = *(const half8*)(Kt + ks * 1024);
      kf[ks][1] = *(const half8*)(Kt + ks * 1024 + 512);
    }
  };
  loadK(0);

  float M = 0.f, Lh = 0.f;
  f32x16 yacc[3];
#pragma unroll
  for (int dt = 0; dt < 3; ++dt)
#pragma unroll
    for (int r = 0; r < 16; ++r) yacc[dt][r] = 0.f;

  for (int t = 0; t < nt; ++t) {
    const _Float16* Vt = Vh + t * 6144;
    half8 vf[4][3];
#pragma unroll
    for (int kt = 0; kt < 4; ++kt)
#pragma unroll
      for (int dt = 0; dt < 3; ++dt)
        vf[kt][dt] = *(const half8*)(Vt + (kt * 3 + dt) * 512);

    const unsigned long long m64 = mbits[b * 16 + t];

    f32x16 s[2];
#pragma unroll
    for (int r = 0; r < 16; ++r) { s[0][r] = 0.f; s[1][r] = 0.f; }
    __builtin_amdgcn_s_setprio(1);
#pragma unroll
    for (int ks = 0; ks < 6; ++ks) {
      s[0] = __builtin_amdgcn_mfma_f32_32x32x16_f16(kf[ks][0], qf[ks], s[0],
                                                    0, 0, 0);
      s[1] = __builtin_amdgcn_mfma_f32_32x32x16_f16(kf[ks][1], qf[ks], s[1],
                                                    0, 0, 0);
    }
    __builtin_amdgcn_s_setprio(0);

    if (t + 1 < nt) loadK(t + 1);

    float mx = -1e30f;
#pragma unroll
    for (int nt2 = 0; nt2 < 2; ++nt2) {
      unsigned wm = (unsigned)(m64 >> (nt2 * 32 + 4 * hi));
#pragma unroll
      for (int r = 0; r < 16; ++r) {
        float sv = s[nt2][r];
        sv = ((wm >> ((r & 3) + 8 * (r >> 2))) & 1u) ? -1e30f : sv;
        s[nt2][r] = sv;
        mx = fmaxf(mx, sv);
      }
    }
    if (__any(mx > M + 12.f)) {
      float mx2 = fmaxf(mx, __shfl_xor(mx, 32));
      float newM = fmaxf(M, mx2);
      float corr = ex2(M - newM);
      M = newM;
      Lh *= corr;
#pragma unroll
      for (int dt = 0; dt < 3; ++dt)
#pragma unroll
        for (int r = 0; r < 16; ++r) yacc[dt][r] *= corr;
    }
    float psum = 0.f;
#pragma unroll
    for (int nt2 = 0; nt2 < 2; ++nt2)
#pragma unroll
      for (int r = 0; r < 16; ++r) {
        float p = ex2(s[nt2][r] - M);
        s[nt2][r] = p;
        psum += p;
      }
    Lh += psum;

#pragma unroll
    for (int nt2 = 0; nt2 < 2; ++nt2) {
#pragma unroll
      for (int hf = 0; hf < 2; ++hf) {
        const int bs = hf * 8;
        unsigned A0 = pkh(s[nt2][bs + 0], s[nt2][bs + 1]);
        unsigned A1 = pkh(s[nt2][bs + 2], s[nt2][bs + 3]);
        unsigned B0 = pkh(s[nt2][bs + 4], s[nt2][bs + 5]);
        unsigned B1 = pkh(s[nt2][bs + 6], s[nt2][bs + 7]);
        plswap(A0, B0);
        plswap(A1, B1);
        PF pf;
        pf.u[0] = A0;
        pf.u[1] = A1;
        pf.u[2] = B0;
        pf.u[3] = B1;
        const int kt = nt2 * 2 + hf;
        __builtin_amdgcn_s_setprio(1);
#pragma unroll
        for (int dt = 0; dt < 3; ++dt)
          yacc[dt] = __builtin_amdgcn_mfma_f32_32x32x16_f16(
              vf[kt][dt], pf.v, yacc[dt], 0, 0, 0);
        __builtin_amdgcn_s_setprio(0);
      }
    }
  }

  float L = Lh + __shfl_xor(Lh, 32);
  float inv = (L > 0.f) ? 1.f / L : 0.f;
  _Float16* yb = yT + (size_t)b * BHN;
#pragma unroll
  for (int dt = 0; dt < 3; ++dt) {
    _Float16* rowp =
        yb + (size_t)(dt * 1024 + n0 + wq0 + lq) * 256 + h * 32 + hi * 4;
#pragma unroll
    for (int g = 0; g < 4; ++g) {
      _Float16 t4[4];
#pragma unroll
      for (int j = 0; j < 4; ++j)
        t4[j] = (_Float16)(yacc[dt][g * 4 + j] * inv);
      *(uint2*)(rowp + g * 8) = *(uint2*)t4;
    }
  }
}

// ---------------------------------------------------------------------------
extern "C" void kernel_launch(void* const* d_in, const int* in_sizes, int n_in,
                              void* d_out, int out_size, void* d_ws,
                              size_t ws_size, hipStream_t stream) {
  const float* x = (const float*)d_in[0];
  const float* Wq = (const float*)d_in[1];
  const float* Wk = (const float*)d_in[2];
  const float* Wv = (const float*)d_in[3];
  const float* Wp = (const float*)d_in[4];
  const unsigned* mask = (const unsigned*)d_in[5];
  float* out = (float*)d_out;

  _Float16* Wh = (_Float16*)d_ws;                   // 0.5 MB
  _Float16* XT = Wh + 4 * 65536;                    // 12.6 MB n-major
  _Float16* Qp = XT + (size_t)B_ * BHN;             // 12.6 MB packed frags
  _Float16* Kp = Qp + (size_t)B_ * BHN;             // 12.6 MB packed frags
  _Float16* Vp = Kp + (size_t)B_ * BHN;             // 12.6 MB packed frags
  _Float16* yT = Vp + (size_t)B_ * BHN;             // 12.6 MB n-major
  unsigned long long* mb = (unsigned long long*)(yT + (size_t)B_ * BHN);
  int* invposArr = (int*)(mb + 128);                // 32 KB
  int* ntArr = invposArr + 8192;                    // 32 B

  prep_kernel<<<dim3(48, 4, 9), 256, 0, stream>>>(x, XT, Wq, Wk, Wv, Wp, Wh,
                                                  mask, mb, invposArr, ntArr);

  dim3 g1(24, 1, B_ * 3);
  mgemm_kernel<0><<<g1, 256, 0, stream>>>(Wh, 0, XT, invposArr, ntArr, Qp, Kp,
                                          Vp, nullptr, 3);

  attn_kernel<<<dim3(512), 256, 0, stream>>>(Qp, Kp, Vp, mb, ntArr, yT);

  dim3 g3(24, 1, B_);
  mgemm_kernel<1><<<g3, 256, 0, stream>>>(Wh, 3, yT, nullptr, nullptr, nullptr,
                                          nullptr, nullptr, out, 1);
}

// Round 20
// 83.979 us; speedup vs baseline: 1.0454x; 1.0454x over previous
//
#include <hip/hip_runtime.h>
#include <hip/hip_bf16.h>
#include <math.h>

#define B_ 8
#define C_ 256
#define N_ 1024
#define H_ 8
#define DH 96
#define BHN (C_*3*N_)
#define SC 0.10206207261596575f     // 1/sqrt(96)
#define SCL2 0.14722193f            // SC * log2(e): QK scores in log2 domain

typedef _Float16 half8 __attribute__((ext_vector_type(8)));
typedef float f32x4 __attribute__((ext_vector_type(4)));
typedef float f32x16 __attribute__((ext_vector_type(16)));

typedef __attribute__((address_space(1))) void gvoid;
typedef __attribute__((address_space(3))) void lvoid;
__device__ inline void gl_lds16(const _Float16* g, _Float16* l) {
  __builtin_amdgcn_global_load_lds((gvoid*)g, (lvoid*)l, 16, 0, 0);
}

__device__ inline float ex2(float x) { return __builtin_amdgcn_exp2f(x); }

typedef __fp16 fp16x2 __attribute__((ext_vector_type(2)));
union H2U { fp16x2 h2; unsigned u; };
__device__ inline unsigned pkh(float a, float b) {
  H2U x; x.h2 = __builtin_amdgcn_cvt_pkrtz(a, b); return x.u;
}
union PF { half8 v; unsigned u[4]; };

// v_permlane32_swap_b32: a' = [a_lo|b_lo], b' = [a_hi|b_hi]
__device__ inline void plswap(unsigned& a, unsigned& b) {
  asm volatile("v_permlane32_swap_b32 %0, %1" : "+v"(a), "+v"(b));
}

// ---------------------------------------------------------------------------
// Fused prep kernel. z<8: transpose-convert x -> XT fp16 n-major.
// z==8 bid<128: W fp32->fp16. bid==128: KEY COMPACTION — stable partition of
// tokens per batch (unmasked -> slots [0,cnt)); emits INVERSE permutation
// invpos[b][slot]=token (gather side), nt[b]=ceil(cnt/64), and per-(b,t)
// bitmask (0 for full tiles, ~0<<rem for the last partial tile).
// ---------------------------------------------------------------------------
__global__ __launch_bounds__(256) void prep_kernel(
    const float* __restrict__ x, _Float16* __restrict__ XT,
    const float* __restrict__ Wq, const float* __restrict__ Wk,
    const float* __restrict__ Wv, const float* __restrict__ Wp,
    _Float16* __restrict__ Wh, const unsigned* __restrict__ mraw,
    unsigned long long* __restrict__ mb, int* __restrict__ invpos,
    int* __restrict__ ntArr) {
  if (blockIdx.z == 8) {
    int bid = blockIdx.y * 48 + blockIdx.x;
    const int tid = threadIdx.x;
    if (bid < 128) {
      int idx = bid * 256 + tid;
      int e0 = idx * 8;
      const float* src = (e0 < 65536) ? Wq
                       : (e0 < 131072) ? Wk
                       : (e0 < 196608) ? Wv : Wp;
      int off = e0 & 65535;
      float4 a = *(const float4*)&src[off];
      float4 b = *(const float4*)&src[off + 4];
      _Float16 t[8] = {(_Float16)a.x, (_Float16)a.y, (_Float16)a.z,
                       (_Float16)a.w, (_Float16)b.x, (_Float16)b.y,
                       (_Float16)b.z, (_Float16)b.w};
      *(uint4*)&Wh[e0] = *(uint4*)t;
    } else if (bid == 128) {
      __shared__ int notI, notF;
      __shared__ int cnts[256];
      if (tid == 0) { notI = 0; notF = 0; }
      __syncthreads();
      int li = 0, lf = 0;
      for (int i = tid; i < 2048; i += 256) {
        unsigned w = mraw[i];
        if (w > 1u) li = 1;
        if (w != 0u && w != 0x3F800000u) lf = 1;
      }
      if (li) atomicOr(&notI, 1);
      if (lf) atomicOr(&notF, 1);
      __syncthreads();
      const int nI = notI, nF = notF;
      auto ispad = [&](int idx) -> int {
        if (!nI) return (int)(mraw[idx] & 1u);
        if (!nF) return (mraw[idx] != 0u) ? 1 : 0;
        return ((const unsigned char*)mraw)[idx] ? 1 : 0;
      };
      const int gb = tid >> 5, gi = tid & 31;   // batch, 32 threads each
      const int tbase = gb * 1024 + gi * 32;    // 32 tokens per thread
      int cloc = 0;
      for (int j = 0; j < 32; ++j) cloc += 1 - ispad(tbase + j);
      cnts[tid] = cloc;
      __syncthreads();
      int pre = 0, tot = 0;
      for (int k2 = 0; k2 < 32; ++k2) {
        int v = cnts[gb * 32 + k2];
        if (k2 < gi) pre += v;
        tot += v;
      }
      int pu = pre;                       // next unmasked compact slot
      int pm = tot + (gi * 32 - pre);     // next masked compact slot
      for (int j = 0; j < 32; ++j) {
        int tok = gi * 32 + j;
        int pd = ispad(tbase + j);
        int p = pd ? pm++ : pu++;
        invpos[gb * 1024 + p] = tok;      // inverse: slot -> token
      }
      if (gi == 0) {
        int nt = (tot + 63) >> 6;
        if (nt == 0) nt = 1;
        ntArr[gb] = nt;
        int rem = tot & 63;
        for (int t = 0; t < 16; ++t) {
          unsigned long long bits;
          if (t < nt - 1) bits = 0ULL;
          else if (t == nt - 1)
            bits = (rem == 0 && tot > 0) ? 0ULL : (~0ULL << rem);
          else bits = ~0ULL;
          mb[gb * 16 + t] = bits;
        }
      }
    }
    return;
  }

  __shared__ _Float16 T[64][65];
  const int m0 = blockIdx.x * 64;
  const int c0 = blockIdx.y * 64;
  const int b = blockIdx.z;
  const float* xb = x + (size_t)b * BHN;
  _Float16* ob = XT + (size_t)b * BHN;
  const int t = threadIdx.x;
#pragma unroll
  for (int i = 0; i < 16; ++i) {
    int e = t + i * 256;
    int c = e >> 6, m = e & 63;
    T[m][c] = (_Float16)xb[(size_t)(c0 + c) * 3072 + m0 + m];
  }
  __syncthreads();
#pragma unroll
  for (int i = 0; i < 2; ++i) {
    int e = t + i * 256;
    int m = e >> 3, ch = e & 7;
    _Float16 tmp[8];
#pragma unroll
    for (int j = 0; j < 8; ++j) tmp[j] = T[m][ch * 8 + j];
    *(uint4*)&ob[(size_t)(m0 + m) * 256 + c0 + ch * 8] = *(uint4*)tmp;
  }
}

// ---------------------------------------------------------------------------
// fp16 MFMA GEMM: O = W(256x256) @ X[b](256x3072), X n-major [n][c].
// BK=64, both-sides XOR chunk swizzle (rule #21). 128x128 tile, (256,4):
// 4 blocks/CU — r19 showed 256-wide o-tile at (256,2) regresses (occupancy).
// MODE 0: k/v (w=1,2) GATHER B-tile rows through invpos during staging and
// write compact-slot outputs coalesced. Blocks whose 128-token range lies
// entirely at slots >= nt[b]*64 (never read by attention) EXIT EARLY.
//   w=0 Qp[bh][qt32][ks6][ql32][hi2][8]  (scaled by SCL2)
//   w=1 Kp[bh][t16][ks6][kk64][hi2][8]   (kk = compact slot)
//   w=2 Vp[bh][t16][kt4][dt3][lq32][hi2][8]
// MODE 1: Of c-major fp32 (final out).
// ---------------------------------------------------------------------------
template <int MODE>
__global__ __launch_bounds__(256, 4) void mgemm_kernel(
    const _Float16* __restrict__ Wh, int woff,
    const _Float16* __restrict__ Xn, const int* __restrict__ invpos,
    const int* __restrict__ ntArr,
    _Float16* __restrict__ O0, _Float16* __restrict__ O1,
    _Float16* __restrict__ O2, float* __restrict__ Of, int nw) {
  const int zz = blockIdx.z;
  const int w = zz % nw;
  const int b = zz / nw;
  const int bn0 = blockIdx.x * 128;

  if constexpr (MODE == 0) {
    // k/v: skip n-tiles fully beyond the compact-slot range used by attn
    if (w != 0 && (bn0 & 1023) >= ntArr[b] * 64) return;
  }

  const _Float16* Wb = Wh + (size_t)(woff + w) * 65536;
  const _Float16* Bb = Xn + (size_t)b * BHN;
  const int o0 = blockIdx.y * 128;

  __shared__ __align__(16) _Float16 Ah[8192];  // [128][64], chunk-swizzled
  __shared__ __align__(16) _Float16 Bh[8192];

  const int tid = threadIdx.x;
  const int wave = tid >> 6;
  const int lane = tid & 63;
  const int lg = lane >> 4, ll = lane & 15;
  const int wm = wave >> 1, wn = wave & 1;

  // per-thread B-tile source rows (fixed across k0); k/v gather via invpos
  int srows[4];
#pragma unroll
  for (int i = 0; i < 4; ++i) {
    int e = tid + i * 256;
    int r = e >> 3;
    int mrow = bn0 + r;
    if constexpr (MODE == 0) {
      if (w != 0) {
        int dd = mrow >> 10, tk = mrow & 1023;
        mrow = dd * 1024 + invpos[b * 1024 + tk];
      }
    }
    srows[i] = mrow;
  }

  f32x4 acc[4][4];
#pragma unroll
  for (int mi = 0; mi < 4; ++mi)
#pragma unroll
    for (int ni = 0; ni < 4; ++ni) acc[mi][ni] = (f32x4){0.f, 0.f, 0.f, 0.f};

  for (int k0 = 0; k0 < 256; k0 += 64) {
#pragma unroll
    for (int i = 0; i < 4; ++i) {
      int e = tid + i * 256;          // chunk id 0..1023
      int r = e >> 3, cch = e & 7;
      int srcc = cch ^ (r & 7);
      _Float16* dst = &Ah[(size_t)(i * 256 + wave * 64) * 8];
      gl_lds16(Wb + (size_t)(o0 + r) * 256 + k0 + srcc * 8, dst);
      _Float16* dstb = &Bh[(size_t)(i * 256 + wave * 64) * 8];
      gl_lds16(Bb + (size_t)srows[i] * 256 + k0 + srcc * 8, dstb);
    }
    __syncthreads();
#pragma unroll
    for (int kk = 0; kk < 2; ++kk) {
      half8 af[4], bf[4];
#pragma unroll
      for (int mi = 0; mi < 4; ++mi) {
        int row = wm * 64 + mi * 16 + ll;
        int ch = (kk * 4 + lg) ^ (row & 7);
        af[mi] = *(const half8*)&Ah[row * 64 + ch * 8];
      }
#pragma unroll
      for (int ni = 0; ni < 4; ++ni) {
        int row = wn * 64 + ni * 16 + ll;
        int ch = (kk * 4 + lg) ^ (row & 7);
        bf[ni] = *(const half8*)&Bh[row * 64 + ch * 8];
      }
#pragma unroll
      for (int mi = 0; mi < 4; ++mi)
#pragma unroll
        for (int ni = 0; ni < 4; ++ni)
          acc[mi][ni] = __builtin_amdgcn_mfma_f32_16x16x32_f16(
              af[mi], bf[ni], acc[mi][ni], 0, 0, 0);
    }
    __syncthreads();
  }

#pragma unroll
  for (int mi = 0; mi < 4; ++mi) {
#pragma unroll
    for (int ni = 0; ni < 4; ++ni) {
      int o = o0 + wm * 64 + mi * 16 + lg * 4;   // channel (4 consecutive via r)
      int mcol = bn0 + wn * 64 + ni * 16 + ll;   // dd*1024 + token/slot
      if constexpr (MODE == 1) {
        float* Ofb = Of + (size_t)b * BHN;
#pragma unroll
        for (int r = 0; r < 4; ++r)
          Ofb[(size_t)(o + r) * 3072 + mcol] = acc[mi][ni][r];
      } else {
        const int h = o >> 5, i = o & 31;
        const int dd = mcol >> 10, tok = mcol & 1023;
        const size_t bh8 = (size_t)(b * 8 + h);
        if (w == 2) {
          // Vp[bh][t][kt][dt=dd][lq=i(+r)][hi2][e]  (tok = compact slot)
          int tt = tok >> 6, kk = tok & 63;
          int kt = kk >> 4, hi2 = (kk >> 3) & 1, e = kk & 7;
          size_t base = ((((bh8 * 16 + tt) * 4 + kt) * 3 + dd) * 512) +
                        (size_t)i * 16 + hi2 * 8 + e;
#pragma unroll
          for (int r = 0; r < 4; ++r)
            O2[base + r * 16] = (_Float16)acc[mi][ni][r];
        } else {
          int dperm = dd * 32 + i;
          int pp = dperm >> 3, j0 = i & 7;
          int ks = pp >> 1, hif = pp & 1;
          float qs = (w == 0) ? SCL2 : 1.0f;
          _Float16 t4[4];
#pragma unroll
          for (int r = 0; r < 4; ++r) t4[r] = (_Float16)(acc[mi][ni][r] * qs);
          size_t idx;
          if (w == 0) {
            // Qp[bh][qt32][ks][ql][hi][j]
            idx = ((bh8 * 32 + (tok >> 5)) * 6 + ks) * 512 +
                  (size_t)(tok & 31) * 16 + hif * 8 + j0;
            *(uint2*)&O0[idx] = *(uint2*)t4;
          } else {
            // Kp[bh][t][ks][kk][hi][j]  (tok = compact slot)
            idx = ((bh8 * 16 + (tok >> 6)) * 6 + ks) * 1024 +
                  (size_t)(tok & 63) * 16 + hif * 8 + j0;
            *(uint2*)&O1[idx] = *(uint2*)t4;
          }
        }
      }
    }
  }
}

// ---------------------------------------------------------------------------
// Flash attention — r9 structure + key compaction (loop over nt[b] tiles).
// 32x32 swapped-QK^T, LDS-free, barrier-free, packed fragment-major q/k/v.
// Softmax exp2 domain, defer-max THR=12, permlane P-repack.
// C/D map: col=lane&31, row=(r&3)+8*(r>>2)+4*(lane>>5).
// ---------------------------------------------------------------------------
__global__ __launch_bounds__(256, 2) void attn_kernel(
    const _Float16* __restrict__ Qp, const _Float16* __restrict__ Kp,
    const _Float16* __restrict__ Vp,
    const unsigned long long* __restrict__ mbits,
    const int* __restrict__ ntArr, _Float16* __restrict__ yT) {
  const int gid = blockIdx.x;
  const int bh = gid & 63;   // XCD = gid%8 = h: per-XCD K/V set L2-resident
  const int qt = gid >> 6;
  const int b = bh >> 3, h = bh & 7;
  const int n0 = qt * 128;
  const int nt = ntArr[b];

  const int tid = threadIdx.x;
  const int lane = tid & 63;
  const int wave = tid >> 6;
  const int hi = lane >> 5;
  const int lq = lane & 31;
  const int wq0 = wave * 32;

  const size_t bh8 = (size_t)(b * 8 + h);
  const int lo16 = lq * 16 + hi * 8;

  const _Float16* Qb = Qp + (bh8 * 32 + (qt * 4 + wave)) * 6 * 512 + lo16;
  half8 qf[6];
#pragma unroll
  for (int ks = 0; ks < 6; ++ks) qf[ks] = *(const half8*)(Qb + ks * 512);

  const _Float16* Kh = Kp + bh8 * 98304 + lo16;
  const _Float16* Vh = Vp + bh8 * 98304 + lo16;

  half8 kf[6][2];
  auto loadK = [&](int t) {
    const _Float16* Kt = Kh + t * 6144;
#pragma unroll
    for (int ks = 0; ks < 6; ++ks) {
      kf[ks][0] = *(const half8*)(Kt + ks * 1024);
      kf[ks][1] = *(const half8*)(Kt + ks * 1024 + 512);
    }
  };
  loadK(0);

  float M = 0.f, Lh = 0.f;
  f32x16 yacc[3];
#pragma unroll
  for (int dt = 0; dt < 3; ++dt)
#pragma unroll
    for (int r = 0; r < 16; ++r) yacc[dt][r] = 0.f;

  for (int t = 0; t < nt; ++t) {
    const _Float16* Vt = Vh + t * 6144;
    half8 vf[4][3];
#pragma unroll
    for (int kt = 0; kt < 4; ++kt)
#pragma unroll
      for (int dt = 0; dt < 3; ++dt)
        vf[kt][dt] = *(const half8*)(Vt + (kt * 3 + dt) * 512);

    const unsigned long long m64 = mbits[b * 16 + t];

    f32x16 s[2];
#pragma unroll
    for (int r = 0; r < 16; ++r) { s[0][r] = 0.f; s[1][r] = 0.f; }
    __builtin_amdgcn_s_setprio(1);
#pragma unroll
    for (int ks = 0; ks < 6; ++ks) {
      s[0] = __builtin_amdgcn_mfma_f32_32x32x16_f16(kf[ks][0], qf[ks], s[0],
                                                    0, 0, 0);
      s[1] = __builtin_amdgcn_mfma_f32_32x32x16_f16(kf[ks][1], qf[ks], s[1],
                                                    0, 0, 0);
    }
    __builtin_amdgcn_s_setprio(0);

    if (t + 1 < nt) loadK(t + 1);

    float mx = -1e30f;
#pragma unroll
    for (int nt2 = 0; nt2 < 2; ++nt2) {
      unsigned wm = (unsigned)(m64 >> (nt2 * 32 + 4 * hi));
#pragma unroll
      for (int r = 0; r < 16; ++r) {
        float sv = s[nt2][r];
        sv = ((wm >> ((r & 3) + 8 * (r >> 2))) & 1u) ? -1e30f : sv;
        s[nt2][r] = sv;
        mx = fmaxf(mx, sv);
      }
    }
    if (__any(mx > M + 12.f)) {
      float mx2 = fmaxf(mx, __shfl_xor(mx, 32));
      float newM = fmaxf(M, mx2);
      float corr = ex2(M - newM);
      M = newM;
      Lh *= corr;
#pragma unroll
      for (int dt = 0; dt < 3; ++dt)
#pragma unroll
        for (int r = 0; r < 16; ++r) yacc[dt][r] *= corr;
    }
    float psum = 0.f;
#pragma unroll
    for (int nt2 = 0; nt2 < 2; ++nt2)
#pragma unroll
      for (int r = 0; r < 16; ++r) {
        float p = ex2(s[nt2][r] - M);
        s[nt2][r] = p;
        psum += p;
      }
    Lh += psum;

#pragma unroll
    for (int nt2 = 0; nt2 < 2; ++nt2) {
#pragma unroll
      for (int hf = 0; hf < 2; ++hf) {
        const int bs = hf * 8;
        unsigned A0 = pkh(s[nt2][bs + 0], s[nt2][bs + 1]);
        unsigned A1 = pkh(s[nt2][bs + 2], s[nt2][bs + 3]);
        unsigned B0 = pkh(s[nt2][bs + 4], s[nt2][bs + 5]);
        unsigned B1 = pkh(s[nt2][bs + 6], s[nt2][bs + 7]);
        plswap(A0, B0);
        plswap(A1, B1);
        PF pf;
        pf.u[0] = A0;
        pf.u[1] = A1;
        pf.u[2] = B0;
        pf.u[3] = B1;
        const int kt = nt2 * 2 + hf;
        __builtin_amdgcn_s_setprio(1);
#pragma unroll
        for (int dt = 0; dt < 3; ++dt)
          yacc[dt] = __builtin_amdgcn_mfma_f32_32x32x16_f16(
              vf[kt][dt], pf.v, yacc[dt], 0, 0, 0);
        __builtin_amdgcn_s_setprio(0);
      }
    }
  }

  float L = Lh + __shfl_xor(Lh, 32);
  float inv = (L > 0.f) ? 1.f / L : 0.f;
  _Float16* yb = yT + (size_t)b * BHN;
#pragma unroll
  for (int dt = 0; dt < 3; ++dt) {
    _Float16* rowp =
        yb + (size_t)(dt * 1024 + n0 + wq0 + lq) * 256 + h * 32 + hi * 4;
#pragma unroll
    for (int g = 0; g < 4; ++g) {
      _Float16 t4[4];
#pragma unroll
      for (int j = 0; j < 4; ++j)
        t4[j] = (_Float16)(yacc[dt][g * 4 + j] * inv);
      *(uint2*)(rowp + g * 8) = *(uint2*)t4;
    }
  }
}

// ---------------------------------------------------------------------------
extern "C" void kernel_launch(void* const* d_in, const int* in_sizes, int n_in,
                              void* d_out, int out_size, void* d_ws,
                              size_t ws_size, hipStream_t stream) {
  const float* x = (const float*)d_in[0];
  const float* Wq = (const float*)d_in[1];
  const float* Wk = (const float*)d_in[2];
  const float* Wv = (const float*)d_in[3];
  const float* Wp = (const float*)d_in[4];
  const unsigned* mask = (const unsigned*)d_in[5];
  float* out = (float*)d_out;

  _Float16* Wh = (_Float16*)d_ws;                   // 0.5 MB
  _Float16* XT = Wh + 4 * 65536;                    // 12.6 MB n-major
  _Float16* Qp = XT + (size_t)B_ * BHN;             // 12.6 MB packed frags
  _Float16* Kp = Qp + (size_t)B_ * BHN;             // 12.6 MB packed frags
  _Float16* Vp = Kp + (size_t)B_ * BHN;             // 12.6 MB packed frags
  _Float16* yT = Vp + (size_t)B_ * BHN;             // 12.6 MB n-major
  unsigned long long* mb = (unsigned long long*)(yT + (size_t)B_ * BHN);
  int* invposArr = (int*)(mb + 128);                // 32 KB
  int* ntArr = invposArr + 8192;                    // 32 B

  prep_kernel<<<dim3(48, 4, 9), 256, 0, stream>>>(x, XT, Wq, Wk, Wv, Wp, Wh,
                                                  mask, mb, invposArr, ntArr);

  dim3 g1(24, 2, B_ * 3);
  mgemm_kernel<0><<<g1, 256, 0, stream>>>(Wh, 0, XT, invposArr, ntArr, Qp, Kp,
                                          Vp, nullptr, 3);

  attn_kernel<<<dim3(512), 256, 0, stream>>>(Qp, Kp, Vp, mb, ntArr, yT);

  dim3 g3(24, 2, B_);
  mgemm_kernel<1><<<g3, 256, 0, stream>>>(Wh, 3, yT, nullptr, nullptr, nullptr,
                                          nullptr, nullptr, out, 1);
}